// Round 1
// baseline (71.737 us; speedup 1.0000x reference)
//
#include <hip/hip_runtime.h>

// SpatialGATAttention fused kernel (MI355X / gfx950)
//
// Shapes: B=8, C=64, T=24, N=512, H=2, D=32, M=B*T=192.
// Design:
//  - Q/K never materialized: s_src = xr . (Wq^T a_src), s_dst = xr . (Wk^T a_dst).
//  - One block per m (192 blocks, 512 threads). All intermediates in LDS.
//  - V projection via mfma_f32_16x16x32_bf16 writing straight into the PV
//    B-fragment LDS layout. PV via same MFMA; attn weights built in-register
//    in the A-fragment lane layout (row = lane&15, k = (lane>>4)*8+e).
//  - Unnormalized softmax (scores bounded, no max pass); normalize + LayerNorm
//    fused in the epilogue using shfl reductions; direct (B,C,T,N) stores.

#define NB 8
#define NC 64
#define NT 24
#define NN 512
#define NM 192

typedef float f32x4 __attribute__((ext_vector_type(4)));
typedef short bf16x8 __attribute__((ext_vector_type(8)));
typedef int   i32x4 __attribute__((ext_vector_type(4)));

__device__ __forceinline__ unsigned short f2bf(float f) {
    union { float f; unsigned int u; } v; v.f = f;
    unsigned int u = v.u;
    u += 0x7fffu + ((u >> 16) & 1u);          // round-to-nearest-even
    return (unsigned short)(u >> 16);
}

__device__ __forceinline__ float bf2f(unsigned short s) {
    union { unsigned int u; float f; } v;
    v.u = ((unsigned int)s) << 16;
    return v.f;
}

// V fragment store layout: [h][k(=j>>5)][q(=(j>>3)&3)][dt][dl][e(=j&7)]
#define VT_IDX(h,k,qq,dt,dl,e) ((((((h)*16+(k))*4+(qq))*2+(dt))*16+(dl))*8+(e))

__global__ __launch_bounds__(512)
void gat_fused(const float* __restrict__ x, const int* __restrict__ gso,
               const float* __restrict__ Wq, const float* __restrict__ Wk,
               const float* __restrict__ Wv, const float* __restrict__ a_src,
               const float* __restrict__ a_dst, const float* __restrict__ gamma,
               const float* __restrict__ beta, float* __restrict__ out)
{
    __shared__ unsigned short sm_xrb[128][72];   // bf16 x-slice chunk [n][c], padded
    __shared__ unsigned short sm_vt[32768];      // bf16 V, B-fragment blocked, 64KB
    __shared__ unsigned short sm_wvb[4096];      // bf16 Wv, B-fragment blocked, 8KB
    __shared__ float sm_ssrc[2][NN];
    __shared__ float sm_sdst[2][NN];
    __shared__ float sm_wqa[2][NC];
    __shared__ float sm_wka[2][NC];

    const int m    = blockIdx.x;
    const int b    = m / NT;
    const int tt   = m % NT;
    const int tid  = threadIdx.x;
    const int lane = tid & 63;
    const int wid  = tid >> 6;
    const int fr   = lane & 15;   // fragment row (A) / col (B, C/D)
    const int fq   = lane >> 4;   // fragment k-chunk selector

    // ---- prep: folded attention vectors wqa = Wq^T a_src, wka = Wk^T a_dst ----
    if (tid < 128) {
        const int h = tid >> 6, c = tid & 63;
        float aq = 0.f, ak = 0.f;
        #pragma unroll
        for (int d = 0; d < 32; ++d) {
            aq += Wq[(h*32 + d)*NC + c] * a_src[h*32 + d];
            ak += Wk[(h*32 + d)*NC + c] * a_dst[h*32 + d];
        }
        sm_wqa[h][c] = aq;
        sm_wka[h][c] = ak;
    }
    // ---- prep: Wv as bf16 B-fragments: [ks][q][dt4][dl][e], c = ks*32+q*8+e ----
    for (int idx = tid; idx < 4096; idx += 512) {
        const int e   = idx & 7;
        const int dl  = (idx >> 3) & 15;
        const int dt4 = (idx >> 7) & 3;
        const int qq  = (idx >> 9) & 3;
        const int ks  = idx >> 11;
        sm_wvb[idx] = f2bf(Wv[(dt4*16 + dl)*NC + ks*32 + qq*8 + e]);
    }
    __syncthreads();

    const int nl = tid >> 2;   // 0..127 : local n within chunk
    const int pp = tid & 3;    // c-quarter

    // ================= projection: 4 chunks of 128 n =================
    for (int ch = 0; ch < 4; ++ch) {
        const int nbase = ch * 128;
        // stage x(b, c, tt, nbase+nl) -> bf16 LDS [n][c]
        #pragma unroll
        for (int half = 0; half < 2; ++half) {
            unsigned short tmp[8];
            #pragma unroll
            for (int e = 0; e < 8; ++e) {
                const int c = pp*16 + half*8 + e;
                tmp[e] = f2bf(x[((size_t)(b*NC + c)*NT + tt)*NN + nbase + nl]);
            }
            *reinterpret_cast<bf16x8*>(&sm_xrb[nl][pp*16 + half*8]) =
                *reinterpret_cast<const bf16x8*>(tmp);
        }
        __syncthreads();

        // ---- scores: s_src/s_dst (fp32, quad-split dot over c) ----
        {
            float sq0=0.f, sq1=0.f, sk0=0.f, sk1=0.f;
            #pragma unroll
            for (int cc = 0; cc < 16; ++cc) {
                const int c = pp*16 + cc;
                const float xv = bf2f(sm_xrb[nl][c]);
                sq0 += xv * sm_wqa[0][c];
                sq1 += xv * sm_wqa[1][c];
                sk0 += xv * sm_wka[0][c];
                sk1 += xv * sm_wka[1][c];
            }
            sq0 += __shfl_xor(sq0,1); sq0 += __shfl_xor(sq0,2);
            sq1 += __shfl_xor(sq1,1); sq1 += __shfl_xor(sq1,2);
            sk0 += __shfl_xor(sk0,1); sk0 += __shfl_xor(sk0,2);
            sk1 += __shfl_xor(sk1,1); sk1 += __shfl_xor(sk1,2);
            if (pp == 0) {
                sm_ssrc[0][nbase+nl] = sq0;
                sm_ssrc[1][nbase+nl] = sq1;
                sm_sdst[0][nbase+nl] = sk0;
                sm_sdst[1][nbase+nl] = sk1;
            }
        }

        // ---- V projection MFMA: wave wid owns n-tile [nbase+wid*16, +16) ----
        {
            f32x4 vacc[4] = {};
            #pragma unroll
            for (int ks = 0; ks < 2; ++ks) {
                const bf16x8 af = *reinterpret_cast<const bf16x8*>(
                    &sm_xrb[wid*16 + fr][ks*32 + fq*8]);
                #pragma unroll
                for (int dt4 = 0; dt4 < 4; ++dt4) {
                    const bf16x8 bfv = *reinterpret_cast<const bf16x8*>(
                        &sm_wvb[(((ks*4 + fq)*4 + dt4)*16 + fr)*8]);
                    vacc[dt4] = __builtin_amdgcn_mfma_f32_16x16x32_bf16(
                        af, bfv, vacc[dt4], 0, 0, 0);
                }
            }
            // scatter D (row = 4*fq+rg -> n, col = fr -> dout) into vt layout
            #pragma unroll
            for (int dt4 = 0; dt4 < 4; ++dt4) {
                const int h = dt4 >> 1, dt = dt4 & 1;
                #pragma unroll
                for (int rg = 0; rg < 4; ++rg) {
                    const int n = nbase + wid*16 + 4*fq + rg;
                    sm_vt[VT_IDX(h, n>>5, (n>>3)&3, dt, fr, n&7)] = f2bf(vacc[dt4][rg]);
                }
            }
        }
        __syncthreads();
    }

    // gamma/beta for this lane's 4 channels (c = dt4*16 + fr)
    float gmv[4], btv[4];
    #pragma unroll
    for (int dt4 = 0; dt4 < 4; ++dt4) {
        gmv[dt4] = gamma[dt4*16 + fr];
        btv[dt4] = beta [dt4*16 + fr];
    }

    // ================= attention: 4 i-tiles of 16 rows per wave =================
    for (int it = 0; it < 4; ++it) {
        const int ibase = (wid*4 + it) * 16;
        const int ig = ibase + fr;                 // this lane's softmax row
        const float src0 = sm_ssrc[0][ig];
        const float src1 = sm_ssrc[1][ig];
        f32x4 acc[4] = {};
        float rsum0 = 0.f, rsum1 = 0.f;

        for (int k = 0; k < 16; ++k) {
            const int j0 = k*32 + fq*8;
            const int* gp = &gso[ig*NN + j0];
            const i32x4 g0 = *reinterpret_cast<const i32x4*>(gp);
            const i32x4 g1 = *reinterpret_cast<const i32x4*>(gp + 4);

            // ---- head 0 ----
            {
                const f32x4 da = *reinterpret_cast<const f32x4*>(&sm_sdst[0][j0]);
                const f32x4 db = *reinterpret_cast<const f32x4*>(&sm_sdst[0][j0+4]);
                bf16x8 af;
                #pragma unroll
                for (int e = 0; e < 4; ++e) {
                    float sc = src0 + da[e];
                    sc = fmaxf(sc, 0.2f*sc);               // leaky_relu
                    float ev = __expf(sc);
                    ev = (g0[e] != 0) ? ev : 0.f;          // mask
                    const unsigned short wb = f2bf(ev);
                    rsum0 += bf2f(wb);                     // sum what MFMA sees
                    af[e] = (short)wb;
                }
                #pragma unroll
                for (int e = 0; e < 4; ++e) {
                    float sc = src0 + db[e];
                    sc = fmaxf(sc, 0.2f*sc);
                    float ev = __expf(sc);
                    ev = (g1[e] != 0) ? ev : 0.f;
                    const unsigned short wb = f2bf(ev);
                    rsum0 += bf2f(wb);
                    af[4+e] = (short)wb;
                }
                const bf16x8 b0 = *reinterpret_cast<const bf16x8*>(&sm_vt[VT_IDX(0,k,fq,0,fr,0)]);
                const bf16x8 b1 = *reinterpret_cast<const bf16x8*>(&sm_vt[VT_IDX(0,k,fq,1,fr,0)]);
                acc[0] = __builtin_amdgcn_mfma_f32_16x16x32_bf16(af, b0, acc[0], 0,0,0);
                acc[1] = __builtin_amdgcn_mfma_f32_16x16x32_bf16(af, b1, acc[1], 0,0,0);
            }
            // ---- head 1 ----
            {
                const f32x4 da = *reinterpret_cast<const f32x4*>(&sm_sdst[1][j0]);
                const f32x4 db = *reinterpret_cast<const f32x4*>(&sm_sdst[1][j0+4]);
                bf16x8 af;
                #pragma unroll
                for (int e = 0; e < 4; ++e) {
                    float sc = src1 + da[e];
                    sc = fmaxf(sc, 0.2f*sc);
                    float ev = __expf(sc);
                    ev = (g0[e] != 0) ? ev : 0.f;
                    const unsigned short wb = f2bf(ev);
                    rsum1 += bf2f(wb);
                    af[e] = (short)wb;
                }
                #pragma unroll
                for (int e = 0; e < 4; ++e) {
                    float sc = src1 + db[e];
                    sc = fmaxf(sc, 0.2f*sc);
                    float ev = __expf(sc);
                    ev = (g1[e] != 0) ? ev : 0.f;
                    const unsigned short wb = f2bf(ev);
                    rsum1 += bf2f(wb);
                    af[4+e] = (short)wb;
                }
                const bf16x8 b0 = *reinterpret_cast<const bf16x8*>(&sm_vt[VT_IDX(1,k,fq,0,fr,0)]);
                const bf16x8 b1 = *reinterpret_cast<const bf16x8*>(&sm_vt[VT_IDX(1,k,fq,1,fr,0)]);
                acc[2] = __builtin_amdgcn_mfma_f32_16x16x32_bf16(af, b0, acc[2], 0,0,0);
                acc[3] = __builtin_amdgcn_mfma_f32_16x16x32_bf16(af, b1, acc[3], 0,0,0);
            }
        }

        // full row sums (lane holds quarter-sum for row ig)
        rsum0 += __shfl_xor(rsum0, 16); rsum0 += __shfl_xor(rsum0, 32);
        rsum1 += __shfl_xor(rsum1, 16); rsum1 += __shfl_xor(rsum1, 32);

        // epilogue: normalize, LayerNorm across 64 channels, store (B,C,T,N)
        #pragma unroll
        for (int rg = 0; rg < 4; ++rg) {
            const int rowloc   = 4*fq + rg;                // C/D row -> i-local
            const int src_lane = (lane & 48) | rowloc;     // lane holding that row's sum
            const float rs0 = __shfl(rsum0, src_lane);
            const float rs1 = __shfl(rsum1, src_lane);
            const float inv0 = 1.f / rs0, inv1 = 1.f / rs1;
            float vv[4];
            vv[0] = acc[0][rg] * inv0;
            vv[1] = acc[1][rg] * inv0;
            vv[2] = acc[2][rg] * inv1;
            vv[3] = acc[3][rg] * inv1;
            float sum = vv[0]+vv[1]+vv[2]+vv[3];
            float ssq = vv[0]*vv[0]+vv[1]*vv[1]+vv[2]*vv[2]+vv[3]*vv[3];
            sum += __shfl_xor(sum,1); sum += __shfl_xor(sum,2);
            sum += __shfl_xor(sum,4); sum += __shfl_xor(sum,8);
            ssq += __shfl_xor(ssq,1); ssq += __shfl_xor(ssq,2);
            ssq += __shfl_xor(ssq,4); ssq += __shfl_xor(ssq,8);
            const float mu   = sum * (1.f/64.f);
            const float var  = ssq * (1.f/64.f) - mu*mu;
            const float rstd = rsqrtf(var + 1e-5f);
            const int irow = ibase + rowloc;
            #pragma unroll
            for (int dt4 = 0; dt4 < 4; ++dt4) {
                const float o = (vv[dt4] - mu) * rstd * gmv[dt4] + btv[dt4];
                out[((size_t)(b*NC + dt4*16 + fr)*NT + tt)*NN + irow] = o;
            }
        }
    }
}

extern "C" void kernel_launch(void* const* d_in, const int* in_sizes, int n_in,
                              void* d_out, int out_size, void* d_ws, size_t ws_size,
                              hipStream_t stream) {
    (void)in_sizes; (void)n_in; (void)d_ws; (void)ws_size; (void)out_size;
    const float* x     = (const float*)d_in[0];
    const int*   gso   = (const int*)  d_in[1];
    const float* Wq    = (const float*)d_in[2];
    const float* Wk    = (const float*)d_in[3];
    const float* Wv    = (const float*)d_in[4];
    const float* a_src = (const float*)d_in[5];
    const float* a_dst = (const float*)d_in[6];
    const float* gamma = (const float*)d_in[7];
    const float* beta  = (const float*)d_in[8];
    float* out = (float*)d_out;

    gat_fused<<<NM, 512, 0, stream>>>(x, gso, Wq, Wk, Wv, a_src, a_dst,
                                      gamma, beta, out);
}

// Round 2
// 56.163 us; speedup vs baseline: 1.2773x; 1.2773x over previous
//
#include <hip/hip_runtime.h>

// SpatialGATAttention — 2-kernel pipeline (MI355X / gfx950)
// k1 (gat_proj, 768 blocks): V -> bf16 MFMA B-fragments in ws; s_src/s_dst
//   pre-scaled by log2(e) in ws; gso -> additive f32 mask {0,-1e9} in ws.
// k2 (gat_attn, 768 blocks = 192 m x 4 i-chunks): stages V (64KB,
//   global_load_lds) + s_dst + s_src, computes exp2(leaky(src+dst+mask))
//   weights directly in A-fragment lane layout (v_perm pack), PV + row-sum
//   via MFMA (ones-column B), fused normalize + LayerNorm epilogue.
// Fallback: proven single-kernel version if ws_size too small.

#define NB 8
#define NC 64
#define NT 24
#define NN 512
#define NM 192
#define LOG2E 1.44269504088896f
#define NEGBIG -1.0e9f

typedef float f32x4 __attribute__((ext_vector_type(4)));
typedef short bf16x8 __attribute__((ext_vector_type(8)));
typedef int   i32x4 __attribute__((ext_vector_type(4)));
typedef unsigned int u32;
typedef u32 u32x2 __attribute__((ext_vector_type(2)));

#ifndef __has_builtin
#define __has_builtin(x) 0
#endif

__device__ __forceinline__ float fast_exp2(float x) {
#if __has_builtin(__builtin_amdgcn_exp2f)
    return __builtin_amdgcn_exp2f(x);
#else
    return exp2f(x);
#endif
}

__device__ __forceinline__ unsigned short f2bf(float f) {
    union { float f; unsigned int u; } v; v.f = f;
    unsigned int u = v.u;
    u += 0x7fffu + ((u >> 16) & 1u);          // round-to-nearest-even
    return (unsigned short)(u >> 16);
}

__device__ __forceinline__ float bf2f(unsigned short s) {
    union { unsigned int u; float f; } v;
    v.u = ((unsigned int)s) << 16;
    return v.f;
}

// V fragment layout: [h][k(=j>>5)][q(=(j>>3)&3)][dt][dl][e(=j&7)]  (u16 idx)
#define VT_IDX(h,k,qq,dt,dl,e) ((((((h)*16+(k))*4+(qq))*2+(dt))*16+(dl))*8+(e))

// ---- workspace layout (bytes) ----
#define WS_VT_OFF   0u                 // u16 [192][32768]  = 12,582,912 B
#define WS_SSRC_OFF 12582912u          // f32 [192][2][512] =    786,432 B
#define WS_SDST_OFF 13369344u          // f32 [192][2][512] =    786,432 B
#define WS_MASK_OFF 14155776u          // f32 [512][512]    =  1,048,576 B
#define WS_NEEDED   15204352u

// =====================================================================
// Kernel 1: projection + score vectors + additive mask
// grid: 768 = (m:192) x (ch:4), block: 512
// =====================================================================
__global__ __launch_bounds__(512)
void gat_proj(const float* __restrict__ x, const int* __restrict__ gso,
              const float* __restrict__ Wq, const float* __restrict__ Wk,
              const float* __restrict__ Wv, const float* __restrict__ a_src,
              const float* __restrict__ a_dst,
              unsigned short* __restrict__ vt_ws, float* __restrict__ ssrc_ws,
              float* __restrict__ sdst_ws, float* __restrict__ mask_ws)
{
    __shared__ unsigned short sm_xrb[128][72];
    __shared__ unsigned short sm_wvb[4096];
    __shared__ float sm_wqa[2][NC];
    __shared__ float sm_wka[2][NC];

    const int bid  = blockIdx.x;
    const int m    = bid >> 2;
    const int ch   = bid & 3;
    const int b    = m / NT;
    const int tt   = m % NT;
    const int tid  = threadIdx.x;
    const int lane = tid & 63;
    const int wid  = tid >> 6;
    const int fr   = lane & 15;
    const int fq   = lane >> 4;

    // ---- additive mask build (first 16 blocks only; 8192 words of 32) ----
    if (bid < 16) {
        const int w  = bid * 512 + tid;
        const int i  = w >> 4, kk = w & 15;
        const int* gp = &gso[i * NN + kk * 32];
        float* mp = &mask_ws[i * NN + kk * 32];
        #pragma unroll
        for (int q = 0; q < 8; ++q) {
            const i32x4 g = *reinterpret_cast<const i32x4*>(gp + q * 4);
            f32x4 f;
            #pragma unroll
            for (int e = 0; e < 4; ++e) f[e] = (g[e] != 0) ? 0.f : NEGBIG;
            *reinterpret_cast<f32x4*>(mp + q * 4) = f;
        }
    }

    // ---- folded attention vectors, pre-scaled by log2(e) ----
    if (tid < 128) {
        const int h = tid >> 6, c = tid & 63;
        float aq = 0.f, ak = 0.f;
        #pragma unroll
        for (int d = 0; d < 32; ++d) {
            aq += Wq[(h*32 + d)*NC + c] * a_src[h*32 + d];
            ak += Wk[(h*32 + d)*NC + c] * a_dst[h*32 + d];
        }
        sm_wqa[h][c] = aq * LOG2E;
        sm_wka[h][c] = ak * LOG2E;
    }
    // ---- Wv as bf16 B-fragments ----
    for (int idx = tid; idx < 4096; idx += 512) {
        const int e   = idx & 7;
        const int dl  = (idx >> 3) & 15;
        const int dt4 = (idx >> 7) & 3;
        const int qq  = (idx >> 9) & 3;
        const int ks  = idx >> 11;
        sm_wvb[idx] = f2bf(Wv[(dt4*16 + dl)*NC + ks*32 + qq*8 + e]);
    }
    __syncthreads();

    const int nl = tid >> 2;        // 0..127 local n
    const int pp = tid & 3;         // c-quarter
    const int nbase = ch * 128;

    // ---- stage x chunk -> bf16 LDS [n][c] ----
    #pragma unroll
    for (int half = 0; half < 2; ++half) {
        unsigned short tmp[8];
        #pragma unroll
        for (int e = 0; e < 8; ++e) {
            const int c = pp*16 + half*8 + e;
            tmp[e] = f2bf(x[((size_t)(b*NC + c)*NT + tt)*NN + nbase + nl]);
        }
        *reinterpret_cast<bf16x8*>(&sm_xrb[nl][pp*16 + half*8]) =
            *reinterpret_cast<const bf16x8*>(tmp);
    }
    __syncthreads();

    // ---- score vectors (fp32 quad-split dot), write to ws ----
    {
        float sq0=0.f, sq1=0.f, sk0=0.f, sk1=0.f;
        #pragma unroll
        for (int cc = 0; cc < 16; ++cc) {
            const int c = pp*16 + cc;
            const float xv = bf2f(sm_xrb[nl][c]);
            sq0 += xv * sm_wqa[0][c];
            sq1 += xv * sm_wqa[1][c];
            sk0 += xv * sm_wka[0][c];
            sk1 += xv * sm_wka[1][c];
        }
        sq0 += __shfl_xor(sq0,1); sq0 += __shfl_xor(sq0,2);
        sq1 += __shfl_xor(sq1,1); sq1 += __shfl_xor(sq1,2);
        sk0 += __shfl_xor(sk0,1); sk0 += __shfl_xor(sk0,2);
        sk1 += __shfl_xor(sk1,1); sk1 += __shfl_xor(sk1,2);
        if (pp == 0) {
            ssrc_ws[((size_t)m*2 + 0)*NN + nbase + nl] = sq0;
            ssrc_ws[((size_t)m*2 + 1)*NN + nbase + nl] = sq1;
            sdst_ws[((size_t)m*2 + 0)*NN + nbase + nl] = sk0;
            sdst_ws[((size_t)m*2 + 1)*NN + nbase + nl] = sk1;
        }
    }

    // ---- V projection MFMA: wave owns n-tile [nbase + wid*16, +16) ----
    {
        f32x4 vacc[4] = {};
        #pragma unroll
        for (int ks = 0; ks < 2; ++ks) {
            const bf16x8 af = *reinterpret_cast<const bf16x8*>(
                &sm_xrb[wid*16 + fr][ks*32 + fq*8]);
            #pragma unroll
            for (int dt4 = 0; dt4 < 4; ++dt4) {
                const bf16x8 bfv = *reinterpret_cast<const bf16x8*>(
                    &sm_wvb[(((ks*4 + fq)*4 + dt4)*16 + fr)*8]);
                vacc[dt4] = __builtin_amdgcn_mfma_f32_16x16x32_bf16(
                    af, bfv, vacc[dt4], 0, 0, 0);
            }
        }
        // write fragments to ws (4 consecutive e per (dt4): one 8B store)
        const int n0 = nbase + wid*16 + 4*fq;    // rg = 0..3 -> e consecutive
        #pragma unroll
        for (int dt4 = 0; dt4 < 4; ++dt4) {
            const int h = dt4 >> 1, dt = dt4 & 1;
            const u32 d0 = (u32)f2bf(vacc[dt4][0]) | ((u32)f2bf(vacc[dt4][1]) << 16);
            const u32 d1 = (u32)f2bf(vacc[dt4][2]) | ((u32)f2bf(vacc[dt4][3]) << 16);
            u32x2 dd; dd[0] = d0; dd[1] = d1;
            *reinterpret_cast<u32x2*>(
                &vt_ws[(size_t)m*32768 + VT_IDX(h, n0>>5, (n0>>3)&3, dt, fr, n0&7)]) = dd;
        }
    }
}

// =====================================================================
// Kernel 2: attention + softmax + PV + LayerNorm
// grid: 768 = (m:192) x (ch:4 i-chunks of 128 rows), block: 512 (8 waves)
// each wave owns one 16-row i-tile
// =====================================================================
__global__ __launch_bounds__(512)
void gat_attn(const unsigned short* __restrict__ vt_ws,
              const float* __restrict__ ssrc_ws, const float* __restrict__ sdst_ws,
              const float* __restrict__ mask_ws,
              const float* __restrict__ gamma, const float* __restrict__ beta,
              float* __restrict__ out)
{
    __shared__ unsigned short sm_vt[32768];      // 64 KB V fragments
    __shared__ float sm_sdst[2][NN];             // 4 KB
    __shared__ float sm_ssrc[2][128];            // 1 KB

    const int bid  = blockIdx.x;
    const int m    = bid >> 2;
    const int ch   = bid & 3;
    const int b    = m / NT;
    const int tt   = m % NT;
    const int tid  = threadIdx.x;
    const int lane = tid & 63;
    const int wid  = tid >> 6;
    const int fr   = lane & 15;
    const int fq   = lane >> 4;

    // ---- stage V fragments: 64KB linear copy ----
    {
        const char* src = (const char*)(vt_ws + (size_t)m * 32768);
#if __has_builtin(__builtin_amdgcn_global_load_lds)
        #pragma unroll
        for (int i = 0; i < 8; ++i) {
            __builtin_amdgcn_global_load_lds(
                (const __attribute__((address_space(1))) void*)
                    (src + i*8192 + tid*16),
                (__attribute__((address_space(3))) void*)
                    (((__attribute__((address_space(3))) char*)sm_vt) +
                     i*8192 + (tid & ~63)*16),
                16, 0, 0);
        }
#else
        #pragma unroll
        for (int i = 0; i < 8; ++i) {
            reinterpret_cast<i32x4*>(sm_vt)[i*512 + tid] =
                reinterpret_cast<const i32x4*>(src)[i*512 + tid];
        }
#endif
    }
    // ---- stage s_dst (both heads, 4KB) and s_src (this chunk, 1KB) ----
    if (tid < 256) {
        reinterpret_cast<f32x4*>(&sm_sdst[0][0])[tid] =
            reinterpret_cast<const f32x4*>(sdst_ws + (size_t)m*2*NN)[tid];
    } else {
        const int t = tid - 256;
        const int h = t >> 7, nloc = t & 127;
        sm_ssrc[h][nloc] = ssrc_ws[((size_t)m*2 + h)*NN + ch*128 + nloc];
    }
    __syncthreads();

    // gamma/beta for this lane's channels (c = dt4*16 + fr)
    float gmv[4], btv[4];
    #pragma unroll
    for (int dt4 = 0; dt4 < 4; ++dt4) {
        gmv[dt4] = gamma[dt4*16 + fr];
        btv[dt4] = beta [dt4*16 + fr];
    }

    // ones-column B fragment (col 0 = 1.0bf16) for MFMA row-sums
    bf16x8 bones;
    {
        union { i32x4 i; bf16x8 h; } cv;
        const int w = (fr == 0) ? 0x3F803F80 : 0;
        cv.i[0] = w; cv.i[1] = w; cv.i[2] = w; cv.i[3] = w;
        bones = cv.h;
    }

    const int iloc = wid * 16;                 // wave's i-tile (local)
    const int ig   = ch*128 + iloc + fr;       // this lane's softmax row
    const float src0 = sm_ssrc[0][iloc + fr];
    const float src1 = sm_ssrc[1][iloc + fr];

    f32x4 acc[4] = {};
    f32x4 accs0 = {}, accs1 = {};

    for (int k = 0; k < 16; ++k) {
        const int j0 = k*32 + fq*8;
        const float* mp = &mask_ws[(size_t)ig * NN + j0];
        const f32x4 ma = *reinterpret_cast<const f32x4*>(mp);
        const f32x4 mb = *reinterpret_cast<const f32x4*>(mp + 4);

        // ---- head 0 ----
        {
            const f32x4 da = *reinterpret_cast<const f32x4*>(&sm_sdst[0][j0]);
            const f32x4 db = *reinterpret_cast<const f32x4*>(&sm_sdst[0][j0+4]);
            u32 u[8];
            #pragma unroll
            for (int e = 0; e < 4; ++e) {
                float sc = src0 + da[e] + ma[e];
                sc = fmaxf(sc, 0.2f*sc);
                u[e] = __float_as_uint(fast_exp2(sc));
            }
            #pragma unroll
            for (int e = 0; e < 4; ++e) {
                float sc = src0 + db[e] + mb[e];
                sc = fmaxf(sc, 0.2f*sc);
                u[4+e] = __float_as_uint(fast_exp2(sc));
            }
            union { i32x4 i; bf16x8 h; } cv;
            cv.i[0] = __builtin_amdgcn_perm(u[1], u[0], 0x07060302u);
            cv.i[1] = __builtin_amdgcn_perm(u[3], u[2], 0x07060302u);
            cv.i[2] = __builtin_amdgcn_perm(u[5], u[4], 0x07060302u);
            cv.i[3] = __builtin_amdgcn_perm(u[7], u[6], 0x07060302u);
            const bf16x8 af = cv.h;
            accs0 = __builtin_amdgcn_mfma_f32_16x16x32_bf16(af, bones, accs0, 0,0,0);
            const bf16x8 b0 = *reinterpret_cast<const bf16x8*>(&sm_vt[VT_IDX(0,k,fq,0,fr,0)]);
            const bf16x8 b1 = *reinterpret_cast<const bf16x8*>(&sm_vt[VT_IDX(0,k,fq,1,fr,0)]);
            acc[0] = __builtin_amdgcn_mfma_f32_16x16x32_bf16(af, b0, acc[0], 0,0,0);
            acc[1] = __builtin_amdgcn_mfma_f32_16x16x32_bf16(af, b1, acc[1], 0,0,0);
        }
        // ---- head 1 ----
        {
            const f32x4 da = *reinterpret_cast<const f32x4*>(&sm_sdst[1][j0]);
            const f32x4 db = *reinterpret_cast<const f32x4*>(&sm_sdst[1][j0+4]);
            u32 u[8];
            #pragma unroll
            for (int e = 0; e < 4; ++e) {
                float sc = src1 + da[e] + ma[e];
                sc = fmaxf(sc, 0.2f*sc);
                u[e] = __float_as_uint(fast_exp2(sc));
            }
            #pragma unroll
            for (int e = 0; e < 4; ++e) {
                float sc = src1 + db[e] + mb[e];
                sc = fmaxf(sc, 0.2f*sc);
                u[4+e] = __float_as_uint(fast_exp2(sc));
            }
            union { i32x4 i; bf16x8 h; } cv;
            cv.i[0] = __builtin_amdgcn_perm(u[1], u[0], 0x07060302u);
            cv.i[1] = __builtin_amdgcn_perm(u[3], u[2], 0x07060302u);
            cv.i[2] = __builtin_amdgcn_perm(u[5], u[4], 0x07060302u);
            cv.i[3] = __builtin_amdgcn_perm(u[7], u[6], 0x07060302u);
            const bf16x8 af = cv.h;
            accs1 = __builtin_amdgcn_mfma_f32_16x16x32_bf16(af, bones, accs1, 0,0,0);
            const bf16x8 b0 = *reinterpret_cast<const bf16x8*>(&sm_vt[VT_IDX(1,k,fq,0,fr,0)]);
            const bf16x8 b1 = *reinterpret_cast<const bf16x8*>(&sm_vt[VT_IDX(1,k,fq,1,fr,0)]);
            acc[2] = __builtin_amdgcn_mfma_f32_16x16x32_bf16(af, b0, acc[2], 0,0,0);
            acc[3] = __builtin_amdgcn_mfma_f32_16x16x32_bf16(af, b1, acc[3], 0,0,0);
        }
    }

    // ---- epilogue: normalize + LayerNorm + store (B,C,T,N) ----
    #pragma unroll
    for (int rg = 0; rg < 4; ++rg) {
        const int rowloc = 4*fq + rg;                  // C/D row (local)
        // row-sum for rowloc lives in lane (fq*16), reg rg, col 0
        const float rs0 = __shfl(accs0[rg], lane & 48);
        const float rs1 = __shfl(accs1[rg], lane & 48);
        const float inv0 = 1.f / rs0, inv1 = 1.f / rs1;
        float vv[4];
        vv[0] = acc[0][rg] * inv0;
        vv[1] = acc[1][rg] * inv0;
        vv[2] = acc[2][rg] * inv1;
        vv[3] = acc[3][rg] * inv1;
        float sum = vv[0]+vv[1]+vv[2]+vv[3];
        float ssq = vv[0]*vv[0]+vv[1]*vv[1]+vv[2]*vv[2]+vv[3]*vv[3];
        sum += __shfl_xor(sum,1); sum += __shfl_xor(sum,2);
        sum += __shfl_xor(sum,4); sum += __shfl_xor(sum,8);
        ssq += __shfl_xor(ssq,1); ssq += __shfl_xor(ssq,2);
        ssq += __shfl_xor(ssq,4); ssq += __shfl_xor(ssq,8);
        const float mu   = sum * (1.f/64.f);
        const float var  = ssq * (1.f/64.f) - mu*mu;
        const float rstd = rsqrtf(var + 1e-5f);
        const int irow = ch*128 + iloc + rowloc;
        #pragma unroll
        for (int dt4 = 0; dt4 < 4; ++dt4) {
            const float o = (vv[dt4] - mu) * rstd * gmv[dt4] + btv[dt4];
            out[((size_t)(b*NC + dt4*16 + fr)*NT + tt)*NN + irow] = o;
        }
    }
}

// =====================================================================
// Fallback: proven single-kernel version (used only if ws too small)
// =====================================================================
__global__ __launch_bounds__(512)
void gat_fused_mono(const float* __restrict__ x, const int* __restrict__ gso,
               const float* __restrict__ Wq, const float* __restrict__ Wk,
               const float* __restrict__ Wv, const float* __restrict__ a_src,
               const float* __restrict__ a_dst, const float* __restrict__ gamma,
               const float* __restrict__ beta, float* __restrict__ out)
{
    __shared__ unsigned short sm_xrb[128][72];
    __shared__ unsigned short sm_vt[32768];
    __shared__ unsigned short sm_wvb[4096];
    __shared__ float sm_ssrc[2][NN];
    __shared__ float sm_sdst[2][NN];
    __shared__ float sm_wqa[2][NC];
    __shared__ float sm_wka[2][NC];

    const int m    = blockIdx.x;
    const int b    = m / NT;
    const int tt   = m % NT;
    const int tid  = threadIdx.x;
    const int lane = tid & 63;
    const int wid  = tid >> 6;
    const int fr   = lane & 15;
    const int fq   = lane >> 4;

    if (tid < 128) {
        const int h = tid >> 6, c = tid & 63;
        float aq = 0.f, ak = 0.f;
        #pragma unroll
        for (int d = 0; d < 32; ++d) {
            aq += Wq[(h*32 + d)*NC + c] * a_src[h*32 + d];
            ak += Wk[(h*32 + d)*NC + c] * a_dst[h*32 + d];
        }
        sm_wqa[h][c] = aq;
        sm_wka[h][c] = ak;
    }
    for (int idx = tid; idx < 4096; idx += 512) {
        const int e   = idx & 7;
        const int dl  = (idx >> 3) & 15;
        const int dt4 = (idx >> 7) & 3;
        const int qq  = (idx >> 9) & 3;
        const int ks  = idx >> 11;
        sm_wvb[idx] = f2bf(Wv[(dt4*16 + dl)*NC + ks*32 + qq*8 + e]);
    }
    __syncthreads();

    const int nl = tid >> 2;
    const int pp = tid & 3;

    for (int ch = 0; ch < 4; ++ch) {
        const int nbase = ch * 128;
        #pragma unroll
        for (int half = 0; half < 2; ++half) {
            unsigned short tmp[8];
            #pragma unroll
            for (int e = 0; e < 8; ++e) {
                const int c = pp*16 + half*8 + e;
                tmp[e] = f2bf(x[((size_t)(b*NC + c)*NT + tt)*NN + nbase + nl]);
            }
            *reinterpret_cast<bf16x8*>(&sm_xrb[nl][pp*16 + half*8]) =
                *reinterpret_cast<const bf16x8*>(tmp);
        }
        __syncthreads();
        {
            float sq0=0.f, sq1=0.f, sk0=0.f, sk1=0.f;
            #pragma unroll
            for (int cc = 0; cc < 16; ++cc) {
                const int c = pp*16 + cc;
                const float xv = bf2f(sm_xrb[nl][c]);
                sq0 += xv * sm_wqa[0][c];
                sq1 += xv * sm_wqa[1][c];
                sk0 += xv * sm_wka[0][c];
                sk1 += xv * sm_wka[1][c];
            }
            sq0 += __shfl_xor(sq0,1); sq0 += __shfl_xor(sq0,2);
            sq1 += __shfl_xor(sq1,1); sq1 += __shfl_xor(sq1,2);
            sk0 += __shfl_xor(sk0,1); sk0 += __shfl_xor(sk0,2);
            sk1 += __shfl_xor(sk1,1); sk1 += __shfl_xor(sk1,2);
            if (pp == 0) {
                sm_ssrc[0][nbase+nl] = sq0;
                sm_ssrc[1][nbase+nl] = sq1;
                sm_sdst[0][nbase+nl] = sk0;
                sm_sdst[1][nbase+nl] = sk1;
            }
        }
        {
            f32x4 vacc[4] = {};
            #pragma unroll
            for (int ks = 0; ks < 2; ++ks) {
                const bf16x8 af = *reinterpret_cast<const bf16x8*>(
                    &sm_xrb[wid*16 + fr][ks*32 + fq*8]);
                #pragma unroll
                for (int dt4 = 0; dt4 < 4; ++dt4) {
                    const bf16x8 bfv = *reinterpret_cast<const bf16x8*>(
                        &sm_wvb[(((ks*4 + fq)*4 + dt4)*16 + fr)*8]);
                    vacc[dt4] = __builtin_amdgcn_mfma_f32_16x16x32_bf16(
                        af, bfv, vacc[dt4], 0, 0, 0);
                }
            }
            #pragma unroll
            for (int dt4 = 0; dt4 < 4; ++dt4) {
                const int h = dt4 >> 1, dt = dt4 & 1;
                #pragma unroll
                for (int rg = 0; rg < 4; ++rg) {
                    const int n = nbase + wid*16 + 4*fq + rg;
                    sm_vt[VT_IDX(h, n>>5, (n>>3)&3, dt, fr, n&7)] = f2bf(vacc[dt4][rg]);
                }
            }
        }
        __syncthreads();
    }

    float gmv[4], btv[4];
    #pragma unroll
    for (int dt4 = 0; dt4 < 4; ++dt4) {
        gmv[dt4] = gamma[dt4*16 + fr];
        btv[dt4] = beta [dt4*16 + fr];
    }

    for (int it = 0; it < 4; ++it) {
        const int ibase = (wid*4 + it) * 16;
        const int ig = ibase + fr;
        const float src0 = sm_ssrc[0][ig];
        const float src1 = sm_ssrc[1][ig];
        f32x4 acc[4] = {};
        float rsum0 = 0.f, rsum1 = 0.f;

        for (int k = 0; k < 16; ++k) {
            const int j0 = k*32 + fq*8;
            const int* gp = &gso[ig*NN + j0];
            const i32x4 g0 = *reinterpret_cast<const i32x4*>(gp);
            const i32x4 g1 = *reinterpret_cast<const i32x4*>(gp + 4);
            {
                const f32x4 da = *reinterpret_cast<const f32x4*>(&sm_sdst[0][j0]);
                const f32x4 db = *reinterpret_cast<const f32x4*>(&sm_sdst[0][j0+4]);
                bf16x8 af;
                #pragma unroll
                for (int e = 0; e < 4; ++e) {
                    float sc = src0 + da[e];
                    sc = fmaxf(sc, 0.2f*sc);
                    float ev = __expf(sc);
                    ev = (g0[e] != 0) ? ev : 0.f;
                    const unsigned short wb = f2bf(ev);
                    rsum0 += bf2f(wb);
                    af[e] = (short)wb;
                }
                #pragma unroll
                for (int e = 0; e < 4; ++e) {
                    float sc = src0 + db[e];
                    sc = fmaxf(sc, 0.2f*sc);
                    float ev = __expf(sc);
                    ev = (g1[e] != 0) ? ev : 0.f;
                    const unsigned short wb = f2bf(ev);
                    rsum0 += bf2f(wb);
                    af[4+e] = (short)wb;
                }
                const bf16x8 b0 = *reinterpret_cast<const bf16x8*>(&sm_vt[VT_IDX(0,k,fq,0,fr,0)]);
                const bf16x8 b1 = *reinterpret_cast<const bf16x8*>(&sm_vt[VT_IDX(0,k,fq,1,fr,0)]);
                acc[0] = __builtin_amdgcn_mfma_f32_16x16x32_bf16(af, b0, acc[0], 0,0,0);
                acc[1] = __builtin_amdgcn_mfma_f32_16x16x32_bf16(af, b1, acc[1], 0,0,0);
            }
            {
                const f32x4 da = *reinterpret_cast<const f32x4*>(&sm_sdst[1][j0]);
                const f32x4 db = *reinterpret_cast<const f32x4*>(&sm_sdst[1][j0+4]);
                bf16x8 af;
                #pragma unroll
                for (int e = 0; e < 4; ++e) {
                    float sc = src1 + da[e];
                    sc = fmaxf(sc, 0.2f*sc);
                    float ev = __expf(sc);
                    ev = (g0[e] != 0) ? ev : 0.f;
                    const unsigned short wb = f2bf(ev);
                    rsum1 += bf2f(wb);
                    af[e] = (short)wb;
                }
                #pragma unroll
                for (int e = 0; e < 4; ++e) {
                    float sc = src1 + db[e];
                    sc = fmaxf(sc, 0.2f*sc);
                    float ev = __expf(sc);
                    ev = (g1[e] != 0) ? ev : 0.f;
                    const unsigned short wb = f2bf(ev);
                    rsum1 += bf2f(wb);
                    af[4+e] = (short)wb;
                }
                const bf16x8 b0 = *reinterpret_cast<const bf16x8*>(&sm_vt[VT_IDX(1,k,fq,0,fr,0)]);
                const bf16x8 b1 = *reinterpret_cast<const bf16x8*>(&sm_vt[VT_IDX(1,k,fq,1,fr,0)]);
                acc[2] = __builtin_amdgcn_mfma_f32_16x16x32_bf16(af, b0, acc[2], 0,0,0);
                acc[3] = __builtin_amdgcn_mfma_f32_16x16x32_bf16(af, b1, acc[3], 0,0,0);
            }
        }

        rsum0 += __shfl_xor(rsum0, 16); rsum0 += __shfl_xor(rsum0, 32);
        rsum1 += __shfl_xor(rsum1, 16); rsum1 += __shfl_xor(rsum1, 32);

        #pragma unroll
        for (int rg = 0; rg < 4; ++rg) {
            const int rowloc   = 4*fq + rg;
            const int src_lane = (lane & 48) | rowloc;
            const float rs0 = __shfl(rsum0, src_lane);
            const float rs1 = __shfl(rsum1, src_lane);
            const float inv0 = 1.f / rs0, inv1 = 1.f / rs1;
            float vv[4];
            vv[0] = acc[0][rg] * inv0;
            vv[1] = acc[1][rg] * inv0;
            vv[2] = acc[2][rg] * inv1;
            vv[3] = acc[3][rg] * inv1;
            float sum = vv[0]+vv[1]+vv[2]+vv[3];
            float ssq = vv[0]*vv[0]+vv[1]*vv[1]+vv[2]*vv[2]+vv[3]*vv[3];
            sum += __shfl_xor(sum,1); sum += __shfl_xor(sum,2);
            sum += __shfl_xor(sum,4); sum += __shfl_xor(sum,8);
            ssq += __shfl_xor(ssq,1); ssq += __shfl_xor(ssq,2);
            ssq += __shfl_xor(ssq,4); ssq += __shfl_xor(ssq,8);
            const float mu   = sum * (1.f/64.f);
            const float var  = ssq * (1.f/64.f) - mu*mu;
            const float rstd = rsqrtf(var + 1e-5f);
            const int irow = ibase + rowloc;
            #pragma unroll
            for (int dt4 = 0; dt4 < 4; ++dt4) {
                const float o = (vv[dt4] - mu) * rstd * gmv[dt4] + btv[dt4];
                out[((size_t)(b*NC + dt4*16 + fr)*NT + tt)*NN + irow] = o;
            }
        }
    }
}

extern "C" void kernel_launch(void* const* d_in, const int* in_sizes, int n_in,
                              void* d_out, int out_size, void* d_ws, size_t ws_size,
                              hipStream_t stream) {
    (void)in_sizes; (void)n_in; (void)out_size;
    const float* x     = (const float*)d_in[0];
    const int*   gso   = (const int*)  d_in[1];
    const float* Wq    = (const float*)d_in[2];
    const float* Wk    = (const float*)d_in[3];
    const float* Wv    = (const float*)d_in[4];
    const float* a_src = (const float*)d_in[5];
    const float* a_dst = (const float*)d_in[6];
    const float* gamma = (const float*)d_in[7];
    const float* beta  = (const float*)d_in[8];
    float* out = (float*)d_out;

    if (ws_size >= (size_t)WS_NEEDED && d_ws != nullptr) {
        unsigned short* vt = (unsigned short*)((char*)d_ws + WS_VT_OFF);
        float* ssrc  = (float*)((char*)d_ws + WS_SSRC_OFF);
        float* sdst  = (float*)((char*)d_ws + WS_SDST_OFF);
        float* maskf = (float*)((char*)d_ws + WS_MASK_OFF);
        gat_proj<<<768, 512, 0, stream>>>(x, gso, Wq, Wk, Wv, a_src, a_dst,
                                          vt, ssrc, sdst, maskf);
        gat_attn<<<768, 512, 0, stream>>>(vt, ssrc, sdst, maskf, gamma, beta, out);
    } else {
        gat_fused_mono<<<NM, 512, 0, stream>>>(x, gso, Wq, Wk, Wv, a_src, a_dst,
                                               gamma, beta, out);
    }
}

// Round 3
// 49.297 us; speedup vs baseline: 1.4552x; 1.1393x over previous
//
#include <hip/hip_runtime.h>

// SpatialGATAttention — 2-kernel pipeline, v2 (MI355X / gfx950)
// Round-3 changes:
//  - attn: V fragments re-laid k-major; staged in 32KB j-halves -> LDS 37.9KB
//    -> 4 blocks/CU capacity (was 2). XCD-swizzled bid so the 4 ch-blocks of
//    one m share an XCD L2 for V re-reads.
//  - proj: x staging coalesced (wave reads 64 consecutive n) + XOR-swizzled
//    LDS x-tile to keep writes conflict-free.

#define NB 8
#define NC 64
#define NT 24
#define NN 512
#define NM 192
#define LOG2E 1.44269504088896f
#define NEGBIG -1.0e9f

typedef float f32x4 __attribute__((ext_vector_type(4)));
typedef short bf16x8 __attribute__((ext_vector_type(8)));
typedef int   i32x4 __attribute__((ext_vector_type(4)));
typedef unsigned int u32;
typedef u32 u32x2 __attribute__((ext_vector_type(2)));

#ifndef __has_builtin
#define __has_builtin(x) 0
#endif

__device__ __forceinline__ float fast_exp2(float x) {
#if __has_builtin(__builtin_amdgcn_exp2f)
    return __builtin_amdgcn_exp2f(x);
#else
    return exp2f(x);
#endif
}

__device__ __forceinline__ unsigned short f2bf(float f) {
    union { float f; unsigned int u; } v; v.f = f;
    unsigned int u = v.u;
    u += 0x7fffu + ((u >> 16) & 1u);          // round-to-nearest-even
    return (unsigned short)(u >> 16);
}

__device__ __forceinline__ float bf2f(unsigned short s) {
    union { unsigned int u; float f; } v;
    v.u = ((unsigned int)s) << 16;
    return v.f;
}

// k-major V fragment layout (u16 index). k2 = j>>5 (0..15 in ws, 0..7 in LDS)
#define VT2_IDX(k2,h,qq,dt,dl,e) \
    ((((((k2)*2+(h))*4+(qq))*2+(dt))*16+(dl))*8+(e))

// swizzled x-tile (u16 index): row n (0..127), col c (0..63); 16B-block XOR
#define XRB(n,c) (((n)<<6) + (((((c)>>3) ^ ((n)&7))<<3) | ((c)&7)))

// old layout for the mono fallback
#define VT_IDX(h,k,qq,dt,dl,e) ((((((h)*16+(k))*4+(qq))*2+(dt))*16+(dl))*8+(e))

// ---- workspace layout (bytes) ----
#define WS_VT_OFF   0u                 // u16 [192][32768]  = 12,582,912 B
#define WS_SSRC_OFF 12582912u          // f32 [192][2][512] =    786,432 B
#define WS_SDST_OFF 13369344u          // f32 [192][2][512] =    786,432 B
#define WS_MASK_OFF 14155776u          // f32 [512][512]    =  1,048,576 B
#define WS_NEEDED   15204352u

// =====================================================================
// Kernel 1: projection + score vectors + additive mask
// grid: 768 = (m:192) x (ch:4), block: 512
// =====================================================================
__global__ __launch_bounds__(512)
void gat_proj(const float* __restrict__ x, const int* __restrict__ gso,
              const float* __restrict__ Wq, const float* __restrict__ Wk,
              const float* __restrict__ Wv, const float* __restrict__ a_src,
              const float* __restrict__ a_dst,
              unsigned short* __restrict__ vt_ws, float* __restrict__ ssrc_ws,
              float* __restrict__ sdst_ws, float* __restrict__ mask_ws)
{
    __shared__ unsigned short sm_xrb[8192];      // swizzled [128][64] bf16, 16KB
    __shared__ unsigned short sm_wvb[4096];
    __shared__ float sm_wqa[2][NC];
    __shared__ float sm_wka[2][NC];

    const int bid  = blockIdx.x;
    const int m    = bid >> 2;
    const int ch   = bid & 3;
    const int b    = m / NT;
    const int tt   = m % NT;
    const int tid  = threadIdx.x;
    const int lane = tid & 63;
    const int wid  = tid >> 6;
    const int fr   = lane & 15;
    const int fq   = lane >> 4;

    // ---- additive mask build (first 16 blocks only) ----
    if (bid < 16) {
        const int w  = bid * 512 + tid;
        const int i  = w >> 4, kk = w & 15;
        const int* gp = &gso[i * NN + kk * 32];
        float* mp = &mask_ws[i * NN + kk * 32];
        #pragma unroll
        for (int q = 0; q < 8; ++q) {
            const i32x4 g = *reinterpret_cast<const i32x4*>(gp + q * 4);
            f32x4 f;
            #pragma unroll
            for (int e = 0; e < 4; ++e) f[e] = (g[e] != 0) ? 0.f : NEGBIG;
            *reinterpret_cast<f32x4*>(mp + q * 4) = f;
        }
    }

    // ---- folded attention vectors, pre-scaled by log2(e) ----
    if (tid < 128) {
        const int h = tid >> 6, c = tid & 63;
        float aq = 0.f, ak = 0.f;
        #pragma unroll
        for (int d = 0; d < 32; ++d) {
            aq += Wq[(h*32 + d)*NC + c] * a_src[h*32 + d];
            ak += Wk[(h*32 + d)*NC + c] * a_dst[h*32 + d];
        }
        sm_wqa[h][c] = aq * LOG2E;
        sm_wka[h][c] = ak * LOG2E;
    }
    // ---- Wv as bf16 B-fragments ----
    for (int idx = tid; idx < 4096; idx += 512) {
        const int e   = idx & 7;
        const int dl  = (idx >> 3) & 15;
        const int dt4 = (idx >> 7) & 3;
        const int qq  = (idx >> 9) & 3;
        const int ks  = idx >> 11;
        sm_wvb[idx] = f2bf(Wv[(dt4*16 + dl)*NC + ks*32 + qq*8 + e]);
    }

    const int nbase = ch * 128;

    // ---- stage x chunk -> swizzled bf16 LDS (coalesced: 64 consecutive n) ----
    {
        const int sl = tid & 127;       // n local
        const int sc = tid >> 7;        // c-quarter
        #pragma unroll
        for (int half = 0; half < 2; ++half) {
            unsigned short tmp[8];
            #pragma unroll
            for (int e = 0; e < 8; ++e) {
                const int c = sc*16 + half*8 + e;
                tmp[e] = f2bf(x[((size_t)(b*NC + c)*NT + tt)*NN + nbase + sl]);
            }
            *reinterpret_cast<bf16x8*>(&sm_xrb[XRB(sl, sc*16 + half*8)]) =
                *reinterpret_cast<const bf16x8*>(tmp);
        }
    }
    __syncthreads();

    // ---- score vectors (fp32 quad-split dot), write to ws ----
    {
        const int nl = tid >> 2;        // 0..127 local n
        const int pp = tid & 3;         // c-quarter
        float sq0=0.f, sq1=0.f, sk0=0.f, sk1=0.f;
        #pragma unroll
        for (int cc = 0; cc < 16; ++cc) {
            const int c = pp*16 + cc;
            const float xv = bf2f(sm_xrb[XRB(nl, c)]);
            sq0 += xv * sm_wqa[0][c];
            sq1 += xv * sm_wqa[1][c];
            sk0 += xv * sm_wka[0][c];
            sk1 += xv * sm_wka[1][c];
        }
        sq0 += __shfl_xor(sq0,1); sq0 += __shfl_xor(sq0,2);
        sq1 += __shfl_xor(sq1,1); sq1 += __shfl_xor(sq1,2);
        sk0 += __shfl_xor(sk0,1); sk0 += __shfl_xor(sk0,2);
        sk1 += __shfl_xor(sk1,1); sk1 += __shfl_xor(sk1,2);
        if (pp == 0) {
            ssrc_ws[((size_t)m*2 + 0)*NN + nbase + nl] = sq0;
            ssrc_ws[((size_t)m*2 + 1)*NN + nbase + nl] = sq1;
            sdst_ws[((size_t)m*2 + 0)*NN + nbase + nl] = sk0;
            sdst_ws[((size_t)m*2 + 1)*NN + nbase + nl] = sk1;
        }
    }

    // ---- V projection MFMA: wave owns n-tile [nbase + wid*16, +16) ----
    {
        f32x4 vacc[4] = {};
        #pragma unroll
        for (int ks = 0; ks < 2; ++ks) {
            const bf16x8 af = *reinterpret_cast<const bf16x8*>(
                &sm_xrb[XRB(wid*16 + fr, ks*32 + fq*8)]);
            #pragma unroll
            for (int dt4 = 0; dt4 < 4; ++dt4) {
                const bf16x8 bfv = *reinterpret_cast<const bf16x8*>(
                    &sm_wvb[(((ks*4 + fq)*4 + dt4)*16 + fr)*8]);
                vacc[dt4] = __builtin_amdgcn_mfma_f32_16x16x32_bf16(
                    af, bfv, vacc[dt4], 0, 0, 0);
            }
        }
        // write fragments to ws (k-major layout; 8B store per dt4)
        const int n0 = nbase + wid*16 + 4*fq;
        #pragma unroll
        for (int dt4 = 0; dt4 < 4; ++dt4) {
            const int h = dt4 >> 1, dt = dt4 & 1;
            const u32 d0 = (u32)f2bf(vacc[dt4][0]) | ((u32)f2bf(vacc[dt4][1]) << 16);
            const u32 d1 = (u32)f2bf(vacc[dt4][2]) | ((u32)f2bf(vacc[dt4][3]) << 16);
            u32x2 dd; dd[0] = d0; dd[1] = d1;
            *reinterpret_cast<u32x2*>(
                &vt_ws[(size_t)m*32768 +
                       VT2_IDX(n0>>5, h, (n0>>3)&3, dt, fr, n0&7)]) = dd;
        }
    }
}

// =====================================================================
// Kernel 2: attention + softmax + PV + LayerNorm
// grid: 768; bid XCD-swizzled so the 4 ch-blocks of one m share an XCD.
// block: 512 (8 waves); each wave owns one 16-row i-tile.
// V staged in two 32KB j-halves -> LDS 37.9KB -> 4 blocks/CU capacity.
// =====================================================================
__global__ __launch_bounds__(512)
void gat_attn(const unsigned short* __restrict__ vt_ws,
              const float* __restrict__ ssrc_ws, const float* __restrict__ sdst_ws,
              const float* __restrict__ mask_ws,
              const float* __restrict__ gamma, const float* __restrict__ beta,
              float* __restrict__ out)
{
    __shared__ unsigned short sm_vt[16384];      // 32 KB: one j-half of V
    __shared__ float sm_sdst[2][NN];             // 4 KB
    __shared__ float sm_ssrc[2][128];            // 1 KB

    const int bid  = blockIdx.x;
    // XCD swizzle: 4 ch-blocks of one m -> same (bid % 8) residue
    const int m    = (bid >> 5) * 8 + (bid & 7);
    const int ch   = (bid >> 3) & 3;
    const int b    = m / NT;
    const int tt   = m % NT;
    const int tid  = threadIdx.x;
    const int lane = tid & 63;
    const int wid  = tid >> 6;
    const int fr   = lane & 15;
    const int fq   = lane >> 4;

    // ---- stage V half 0 (async) + score vectors ----
    const char* vsrc = (const char*)(vt_ws + (size_t)m * 32768);
#if __has_builtin(__builtin_amdgcn_global_load_lds)
    #pragma unroll
    for (int i = 0; i < 4; ++i) {
        __builtin_amdgcn_global_load_lds(
            (const __attribute__((address_space(1))) void*)
                (vsrc + i*8192 + tid*16),
            (__attribute__((address_space(3))) void*)
                (((__attribute__((address_space(3))) char*)sm_vt) +
                 i*8192 + (tid & ~63)*16),
            16, 0, 0);
    }
#else
    #pragma unroll
    for (int i = 0; i < 4; ++i) {
        reinterpret_cast<i32x4*>(sm_vt)[i*512 + tid] =
            reinterpret_cast<const i32x4*>(vsrc)[i*512 + tid];
    }
#endif
    if (tid < 256) {
        reinterpret_cast<f32x4*>(&sm_sdst[0][0])[tid] =
            reinterpret_cast<const f32x4*>(sdst_ws + (size_t)m*2*NN)[tid];
    } else {
        const int t = tid - 256;
        const int h = t >> 7, nloc = t & 127;
        sm_ssrc[h][nloc] = ssrc_ws[((size_t)m*2 + h)*NN + ch*128 + nloc];
    }
    __syncthreads();

    // gamma/beta for this lane's channels (c = dt4*16 + fr)
    float gmv[4], btv[4];
    #pragma unroll
    for (int dt4 = 0; dt4 < 4; ++dt4) {
        gmv[dt4] = gamma[dt4*16 + fr];
        btv[dt4] = beta [dt4*16 + fr];
    }

    // ones-column B fragment (col 0 = 1.0bf16) for MFMA row-sums
    bf16x8 bones;
    {
        union { i32x4 i; bf16x8 h; } cv;
        const int w = (fr == 0) ? 0x3F803F80 : 0;
        cv.i[0] = w; cv.i[1] = w; cv.i[2] = w; cv.i[3] = w;
        bones = cv.h;
    }

    const int iloc = wid * 16;
    const int ig   = ch*128 + iloc + fr;
    const float src0 = sm_ssrc[0][iloc + fr];
    const float src1 = sm_ssrc[1][iloc + fr];
    const float* mrow = mask_ws + (size_t)ig * NN;

    f32x4 acc[4] = {};
    f32x4 accs0 = {}, accs1 = {};

    #pragma unroll
    for (int hf = 0; hf < 2; ++hf) {
        for (int k2 = 0; k2 < 8; ++k2) {
            const int k  = hf*8 + k2;
            const int j0 = k*32 + fq*8;
            const float* mp = mrow + j0;
            const f32x4 ma = *reinterpret_cast<const f32x4*>(mp);
            const f32x4 mb = *reinterpret_cast<const f32x4*>(mp + 4);

            // ---- head 0 ----
            {
                const f32x4 da = *reinterpret_cast<const f32x4*>(&sm_sdst[0][j0]);
                const f32x4 db = *reinterpret_cast<const f32x4*>(&sm_sdst[0][j0+4]);
                u32 u[8];
                #pragma unroll
                for (int e = 0; e < 4; ++e) {
                    float sc = src0 + da[e] + ma[e];
                    sc = fmaxf(sc, 0.2f*sc);
                    u[e] = __float_as_uint(fast_exp2(sc));
                }
                #pragma unroll
                for (int e = 0; e < 4; ++e) {
                    float sc = src0 + db[e] + mb[e];
                    sc = fmaxf(sc, 0.2f*sc);
                    u[4+e] = __float_as_uint(fast_exp2(sc));
                }
                union { i32x4 i; bf16x8 h; } cv;
                cv.i[0] = __builtin_amdgcn_perm(u[1], u[0], 0x07060302u);
                cv.i[1] = __builtin_amdgcn_perm(u[3], u[2], 0x07060302u);
                cv.i[2] = __builtin_amdgcn_perm(u[5], u[4], 0x07060302u);
                cv.i[3] = __builtin_amdgcn_perm(u[7], u[6], 0x07060302u);
                const bf16x8 af = cv.h;
                accs0 = __builtin_amdgcn_mfma_f32_16x16x32_bf16(af, bones, accs0, 0,0,0);
                const bf16x8 b0 = *reinterpret_cast<const bf16x8*>(
                    &sm_vt[VT2_IDX(k2,0,fq,0,fr,0)]);
                const bf16x8 b1 = *reinterpret_cast<const bf16x8*>(
                    &sm_vt[VT2_IDX(k2,0,fq,1,fr,0)]);
                acc[0] = __builtin_amdgcn_mfma_f32_16x16x32_bf16(af, b0, acc[0], 0,0,0);
                acc[1] = __builtin_amdgcn_mfma_f32_16x16x32_bf16(af, b1, acc[1], 0,0,0);
            }
            // ---- head 1 ----
            {
                const f32x4 da = *reinterpret_cast<const f32x4*>(&sm_sdst[1][j0]);
                const f32x4 db = *reinterpret_cast<const f32x4*>(&sm_sdst[1][j0+4]);
                u32 u[8];
                #pragma unroll
                for (int e = 0; e < 4; ++e) {
                    float sc = src1 + da[e] + ma[e];
                    sc = fmaxf(sc, 0.2f*sc);
                    u[e] = __float_as_uint(fast_exp2(sc));
                }
                #pragma unroll
                for (int e = 0; e < 4; ++e) {
                    float sc = src1 + db[e] + mb[e];
                    sc = fmaxf(sc, 0.2f*sc);
                    u[4+e] = __float_as_uint(fast_exp2(sc));
                }
                union { i32x4 i; bf16x8 h; } cv;
                cv.i[0] = __builtin_amdgcn_perm(u[1], u[0], 0x07060302u);
                cv.i[1] = __builtin_amdgcn_perm(u[3], u[2], 0x07060302u);
                cv.i[2] = __builtin_amdgcn_perm(u[5], u[4], 0x07060302u);
                cv.i[3] = __builtin_amdgcn_perm(u[7], u[6], 0x07060302u);
                const bf16x8 af = cv.h;
                accs1 = __builtin_amdgcn_mfma_f32_16x16x32_bf16(af, bones, accs1, 0,0,0);
                const bf16x8 b0 = *reinterpret_cast<const bf16x8*>(
                    &sm_vt[VT2_IDX(k2,1,fq,0,fr,0)]);
                const bf16x8 b1 = *reinterpret_cast<const bf16x8*>(
                    &sm_vt[VT2_IDX(k2,1,fq,1,fr,0)]);
                acc[2] = __builtin_amdgcn_mfma_f32_16x16x32_bf16(af, b0, acc[2], 0,0,0);
                acc[3] = __builtin_amdgcn_mfma_f32_16x16x32_bf16(af, b1, acc[3], 0,0,0);
            }
        }

        if (hf == 0) {
            // all waves done reading half 0; re-stage half 1 into same buffer
            __syncthreads();
#if __has_builtin(__builtin_amdgcn_global_load_lds)
            #pragma unroll
            for (int i = 0; i < 4; ++i) {
                __builtin_amdgcn_global_load_lds(
                    (const __attribute__((address_space(1))) void*)
                        (vsrc + 32768 + i*8192 + tid*16),
                    (__attribute__((address_space(3))) void*)
                        (((__attribute__((address_space(3))) char*)sm_vt) +
                         i*8192 + (tid & ~63)*16),
                    16, 0, 0);
            }
#else
            #pragma unroll
            for (int i = 0; i < 4; ++i) {
                reinterpret_cast<i32x4*>(sm_vt)[i*512 + tid] =
                    reinterpret_cast<const i32x4*>(vsrc + 32768)[i*512 + tid];
            }
#endif
            __syncthreads();
        }
    }

    // ---- epilogue: normalize + LayerNorm + store (B,C,T,N) ----
    #pragma unroll
    for (int rg = 0; rg < 4; ++rg) {
        const int rowloc = 4*fq + rg;
        const float rs0 = __shfl(accs0[rg], lane & 48);
        const float rs1 = __shfl(accs1[rg], lane & 48);
        const float inv0 = 1.f / rs0, inv1 = 1.f / rs1;
        float vv[4];
        vv[0] = acc[0][rg] * inv0;
        vv[1] = acc[1][rg] * inv0;
        vv[2] = acc[2][rg] * inv1;
        vv[3] = acc[3][rg] * inv1;
        float sum = vv[0]+vv[1]+vv[2]+vv[3];
        float ssq = vv[0]*vv[0]+vv[1]*vv[1]+vv[2]*vv[2]+vv[3]*vv[3];
        sum += __shfl_xor(sum,1); sum += __shfl_xor(sum,2);
        sum += __shfl_xor(sum,4); sum += __shfl_xor(sum,8);
        ssq += __shfl_xor(ssq,1); ssq += __shfl_xor(ssq,2);
        ssq += __shfl_xor(ssq,4); ssq += __shfl_xor(ssq,8);
        const float mu   = sum * (1.f/64.f);
        const float var  = ssq * (1.f/64.f) - mu*mu;
        const float rstd = rsqrtf(var + 1e-5f);
        const int irow = ch*128 + iloc + rowloc;
        #pragma unroll
        for (int dt4 = 0; dt4 < 4; ++dt4) {
            const float o = (vv[dt4] - mu) * rstd * gmv[dt4] + btv[dt4];
            out[((size_t)(b*NC + dt4*16 + fr)*NT + tt)*NN + irow] = o;
        }
    }
}

// =====================================================================
// Fallback: proven single-kernel version (used only if ws too small)
// =====================================================================
__global__ __launch_bounds__(512)
void gat_fused_mono(const float* __restrict__ x, const int* __restrict__ gso,
               const float* __restrict__ Wq, const float* __restrict__ Wk,
               const float* __restrict__ Wv, const float* __restrict__ a_src,
               const float* __restrict__ a_dst, const float* __restrict__ gamma,
               const float* __restrict__ beta, float* __restrict__ out)
{
    __shared__ unsigned short sm_xrb[128][72];
    __shared__ unsigned short sm_vt[32768];
    __shared__ unsigned short sm_wvb[4096];
    __shared__ float sm_ssrc[2][NN];
    __shared__ float sm_sdst[2][NN];
    __shared__ float sm_wqa[2][NC];
    __shared__ float sm_wka[2][NC];

    const int m    = blockIdx.x;
    const int b    = m / NT;
    const int tt   = m % NT;
    const int tid  = threadIdx.x;
    const int lane = tid & 63;
    const int wid  = tid >> 6;
    const int fr   = lane & 15;
    const int fq   = lane >> 4;

    if (tid < 128) {
        const int h = tid >> 6, c = tid & 63;
        float aq = 0.f, ak = 0.f;
        #pragma unroll
        for (int d = 0; d < 32; ++d) {
            aq += Wq[(h*32 + d)*NC + c] * a_src[h*32 + d];
            ak += Wk[(h*32 + d)*NC + c] * a_dst[h*32 + d];
        }
        sm_wqa[h][c] = aq;
        sm_wka[h][c] = ak;
    }
    for (int idx = tid; idx < 4096; idx += 512) {
        const int e   = idx & 7;
        const int dl  = (idx >> 3) & 15;
        const int dt4 = (idx >> 7) & 3;
        const int qq  = (idx >> 9) & 3;
        const int ks  = idx >> 11;
        sm_wvb[idx] = f2bf(Wv[(dt4*16 + dl)*NC + ks*32 + qq*8 + e]);
    }
    __syncthreads();

    const int nl = tid >> 2;
    const int pp = tid & 3;

    for (int ch = 0; ch < 4; ++ch) {
        const int nbase = ch * 128;
        #pragma unroll
        for (int half = 0; half < 2; ++half) {
            unsigned short tmp[8];
            #pragma unroll
            for (int e = 0; e < 8; ++e) {
                const int c = pp*16 + half*8 + e;
                tmp[e] = f2bf(x[((size_t)(b*NC + c)*NT + tt)*NN + nbase + nl]);
            }
            *reinterpret_cast<bf16x8*>(&sm_xrb[nl][pp*16 + half*8]) =
                *reinterpret_cast<const bf16x8*>(tmp);
        }
        __syncthreads();
        {
            float sq0=0.f, sq1=0.f, sk0=0.f, sk1=0.f;
            #pragma unroll
            for (int cc = 0; cc < 16; ++cc) {
                const int c = pp*16 + cc;
                const float xv = bf2f(sm_xrb[nl][c]);
                sq0 += xv * sm_wqa[0][c];
                sq1 += xv * sm_wqa[1][c];
                sk0 += xv * sm_wka[0][c];
                sk1 += xv * sm_wka[1][c];
            }
            sq0 += __shfl_xor(sq0,1); sq0 += __shfl_xor(sq0,2);
            sq1 += __shfl_xor(sq1,1); sq1 += __shfl_xor(sq1,2);
            sk0 += __shfl_xor(sk0,1); sk0 += __shfl_xor(sk0,2);
            sk1 += __shfl_xor(sk1,1); sk1 += __shfl_xor(sk1,2);
            if (pp == 0) {
                sm_ssrc[0][nbase+nl] = sq0;
                sm_ssrc[1][nbase+nl] = sq1;
                sm_sdst[0][nbase+nl] = sk0;
                sm_sdst[1][nbase+nl] = sk1;
            }
        }
        {
            f32x4 vacc[4] = {};
            #pragma unroll
            for (int ks = 0; ks < 2; ++ks) {
                const bf16x8 af = *reinterpret_cast<const bf16x8*>(
                    &sm_xrb[wid*16 + fr][ks*32 + fq*8]);
                #pragma unroll
                for (int dt4 = 0; dt4 < 4; ++dt4) {
                    const bf16x8 bfv = *reinterpret_cast<const bf16x8*>(
                        &sm_wvb[(((ks*4 + fq)*4 + dt4)*16 + fr)*8]);
                    vacc[dt4] = __builtin_amdgcn_mfma_f32_16x16x32_bf16(
                        af, bfv, vacc[dt4], 0, 0, 0);
                }
            }
            #pragma unroll
            for (int dt4 = 0; dt4 < 4; ++dt4) {
                const int h = dt4 >> 1, dt = dt4 & 1;
                #pragma unroll
                for (int rg = 0; rg < 4; ++rg) {
                    const int n = nbase + wid*16 + 4*fq + rg;
                    sm_vt[VT_IDX(h, n>>5, (n>>3)&3, dt, fr, n&7)] = f2bf(vacc[dt4][rg]);
                }
            }
        }
        __syncthreads();
    }

    float gmv[4], btv[4];
    #pragma unroll
    for (int dt4 = 0; dt4 < 4; ++dt4) {
        gmv[dt4] = gamma[dt4*16 + fr];
        btv[dt4] = beta [dt4*16 + fr];
    }

    for (int it = 0; it < 4; ++it) {
        const int ibase = (wid*4 + it) * 16;
        const int ig = ibase + fr;
        const float src0 = sm_ssrc[0][ig];
        const float src1 = sm_ssrc[1][ig];
        f32x4 acc[4] = {};
        float rsum0 = 0.f, rsum1 = 0.f;

        for (int k = 0; k < 16; ++k) {
            const int j0 = k*32 + fq*8;
            const int* gp = &gso[ig*NN + j0];
            const i32x4 g0 = *reinterpret_cast<const i32x4*>(gp);
            const i32x4 g1 = *reinterpret_cast<const i32x4*>(gp + 4);
            {
                const f32x4 da = *reinterpret_cast<const f32x4*>(&sm_sdst[0][j0]);
                const f32x4 db = *reinterpret_cast<const f32x4*>(&sm_sdst[0][j0+4]);
                bf16x8 af;
                #pragma unroll
                for (int e = 0; e < 4; ++e) {
                    float sc = src0 + da[e];
                    sc = fmaxf(sc, 0.2f*sc);
                    float ev = __expf(sc);
                    ev = (g0[e] != 0) ? ev : 0.f;
                    const unsigned short wb = f2bf(ev);
                    rsum0 += bf2f(wb);
                    af[e] = (short)wb;
                }
                #pragma unroll
                for (int e = 0; e < 4; ++e) {
                    float sc = src0 + db[e];
                    sc = fmaxf(sc, 0.2f*sc);
                    float ev = __expf(sc);
                    ev = (g1[e] != 0) ? ev : 0.f;
                    const unsigned short wb = f2bf(ev);
                    rsum0 += bf2f(wb);
                    af[4+e] = (short)wb;
                }
                const bf16x8 b0 = *reinterpret_cast<const bf16x8*>(&sm_vt[VT_IDX(0,k,fq,0,fr,0)]);
                const bf16x8 b1 = *reinterpret_cast<const bf16x8*>(&sm_vt[VT_IDX(0,k,fq,1,fr,0)]);
                acc[0] = __builtin_amdgcn_mfma_f32_16x16x32_bf16(af, b0, acc[0], 0,0,0);
                acc[1] = __builtin_amdgcn_mfma_f32_16x16x32_bf16(af, b1, acc[1], 0,0,0);
            }
            {
                const f32x4 da = *reinterpret_cast<const f32x4*>(&sm_sdst[1][j0]);
                const f32x4 db = *reinterpret_cast<const f32x4*>(&sm_sdst[1][j0+4]);
                bf16x8 af;
                #pragma unroll
                for (int e = 0; e < 4; ++e) {
                    float sc = src1 + da[e];
                    sc = fmaxf(sc, 0.2f*sc);
                    float ev = __expf(sc);
                    ev = (g0[e] != 0) ? ev : 0.f;
                    const unsigned short wb = f2bf(ev);
                    rsum1 += bf2f(wb);
                    af[e] = (short)wb;
                }
                #pragma unroll
                for (int e = 0; e < 4; ++e) {
                    float sc = src1 + db[e];
                    sc = fmaxf(sc, 0.2f*sc);
                    float ev = __expf(sc);
                    ev = (g1[e] != 0) ? ev : 0.f;
                    const unsigned short wb = f2bf(ev);
                    rsum1 += bf2f(wb);
                    af[4+e] = (short)wb;
                }
                const bf16x8 b0 = *reinterpret_cast<const bf16x8*>(&sm_vt[VT_IDX(1,k,fq,0,fr,0)]);
                const bf16x8 b1 = *reinterpret_cast<const bf16x8*>(&sm_vt[VT_IDX(1,k,fq,1,fr,0)]);
                acc[2] = __builtin_amdgcn_mfma_f32_16x16x32_bf16(af, b0, acc[2], 0,0,0);
                acc[3] = __builtin_amdgcn_mfma_f32_16x16x32_bf16(af, b1, acc[3], 0,0,0);
            }
        }

        rsum0 += __shfl_xor(rsum0, 16); rsum0 += __shfl_xor(rsum0, 32);
        rsum1 += __shfl_xor(rsum1, 16); rsum1 += __shfl_xor(rsum1, 32);

        #pragma unroll
        for (int rg = 0; rg < 4; ++rg) {
            const int rowloc   = 4*fq + rg;
            const int src_lane = (lane & 48) | rowloc;
            const float rs0 = __shfl(rsum0, src_lane);
            const float rs1 = __shfl(rsum1, src_lane);
            const float inv0 = 1.f / rs0, inv1 = 1.f / rs1;
            float vv[4];
            vv[0] = acc[0][rg] * inv0;
            vv[1] = acc[1][rg] * inv0;
            vv[2] = acc[2][rg] * inv1;
            vv[3] = acc[3][rg] * inv1;
            float sum = vv[0]+vv[1]+vv[2]+vv[3];
            float ssq = vv[0]*vv[0]+vv[1]*vv[1]+vv[2]*vv[2]+vv[3]*vv[3];
            sum += __shfl_xor(sum,1); sum += __shfl_xor(sum,2);
            sum += __shfl_xor(sum,4); sum += __shfl_xor(sum,8);
            ssq += __shfl_xor(ssq,1); ssq += __shfl_xor(ssq,2);
            ssq += __shfl_xor(ssq,4); ssq += __shfl_xor(ssq,8);
            const float mu   = sum * (1.f/64.f);
            const float var  = ssq * (1.f/64.f) - mu*mu;
            const float rstd = rsqrtf(var + 1e-5f);
            const int irow = ibase + rowloc;
            #pragma unroll
            for (int dt4 = 0; dt4 < 4; ++dt4) {
                const float o = (vv[dt4] - mu) * rstd * gmv[dt4] + btv[dt4];
                out[((size_t)(b*NC + dt4*16 + fr)*NT + tt)*NN + irow] = o;
            }
        }
    }
}

extern "C" void kernel_launch(void* const* d_in, const int* in_sizes, int n_in,
                              void* d_out, int out_size, void* d_ws, size_t ws_size,
                              hipStream_t stream) {
    (void)in_sizes; (void)n_in; (void)out_size;
    const float* x     = (const float*)d_in[0];
    const int*   gso   = (const int*)  d_in[1];
    const float* Wq    = (const float*)d_in[2];
    const float* Wk    = (const float*)d_in[3];
    const float* Wv    = (const float*)d_in[4];
    const float* a_src = (const float*)d_in[5];
    const float* a_dst = (const float*)d_in[6];
    const float* gamma = (const float*)d_in[7];
    const float* beta  = (const float*)d_in[8];
    float* out = (float*)d_out;

    if (ws_size >= (size_t)WS_NEEDED && d_ws != nullptr) {
        unsigned short* vt = (unsigned short*)((char*)d_ws + WS_VT_OFF);
        float* ssrc  = (float*)((char*)d_ws + WS_SSRC_OFF);
        float* sdst  = (float*)((char*)d_ws + WS_SDST_OFF);
        float* maskf = (float*)((char*)d_ws + WS_MASK_OFF);
        gat_proj<<<768, 512, 0, stream>>>(x, gso, Wq, Wk, Wv, a_src, a_dst,
                                          vt, ssrc, sdst, maskf);
        gat_attn<<<768, 512, 0, stream>>>(vt, ssrc, sdst, maskf, gamma, beta, out);
    } else {
        gat_fused_mono<<<NM, 512, 0, stream>>>(x, gso, Wq, Wk, Wv, a_src, a_dst,
                                               gamma, beta, out);
    }
}